// Round 1
// 73.081 us; speedup vs baseline: 1.1707x; 1.1707x over previous
//
#include <hip/hip_runtime.h>
#include <math.h>

#define BN 256      // batch
#define CN 2048     // channels
#define C4 512      // CN/4
#define EPSF 1e-12f

// ---------------------------------------------------------------------------
// Kernel A: raw Gram D = in @ in^T (256x256, K=2048), fp32, SYMMETRIC.
// Grid 512 (tile ib=b>>3 of 4 i-rows, jb=b&7 of 32 j-cols); tiles entirely in
// the strict lower triangle (32*jb+31 < 4*ib) exit early — their region is
// covered by the mirror store of the transposed tile. D[i,j] and D[j,i] are
// bitwise identical (commutative products, same summation order), so double
// writes on straddling tiles are benign. Block 64 (always an exit block)
// zeroes out[0] for finish's atomicAdd; kernel boundary orders it.
// Per kept tile: 4 i-rows in 128 VGPRs (wave-invariant), per j 8 coalesced
// float4 loads + 128 FMAs + 7-shuffle merge-tree; lanes 0-3 store c and its
// mirror. L2 traffic 147 MB -> ~83 MB, FMAs x0.56.
// __launch_bounds__(256,1): round 3 showed demoting a[4][8] costs ~10x.
// UNCHANGED this round (isolating the finish_kernel delta).
// ---------------------------------------------------------------------------
__global__ __launch_bounds__(256, 1) void gram_kernel(const float* __restrict__ in,
                                                      float* __restrict__ D,
                                                      float* __restrict__ out) {
    const int b   = blockIdx.x;
    const int ib  = b >> 3;
    const int jb  = b & 7;
    const int tid = threadIdx.x;

    if (32 * jb + 31 < 4 * ib) {           // strictly-lower tile: mirror-covered
        if (b == 64 && tid == 0) out[0] = 0.f;
        return;
    }

    const int i0   = ib * 4;
    const int j0   = jb * 32;
    const int lane = tid & 63;
    const int wave = tid >> 6;
    const bool odd1 = (lane & 1);
    const bool odd2 = (lane & 2);

    const float4* __restrict__ in4 = (const float4*)in;

    float4 a[4][8];
#pragma unroll
    for (int r = 0; r < 4; ++r)
#pragma unroll
        for (int t = 0; t < 8; ++t)
            a[r][t] = in4[(i0 + r) * C4 + lane + 64 * t];

#pragma unroll 2
    for (int s = 0; s < 8; ++s) {
        const int j = j0 + wave + 4 * s;
        float4 bv[8];
#pragma unroll
        for (int t = 0; t < 8; ++t)
            bv[t] = in4[j * C4 + lane + 64 * t];

        float a0 = 0.f, a1 = 0.f, a2 = 0.f, a3 = 0.f;
#pragma unroll
        for (int t = 0; t < 8; ++t) {
            const float4 b4 = bv[t];
            a0 += a[0][t].x * b4.x + a[0][t].y * b4.y + a[0][t].z * b4.z + a[0][t].w * b4.w;
            a1 += a[1][t].x * b4.x + a[1][t].y * b4.y + a[1][t].z * b4.z + a[1][t].w * b4.w;
            a2 += a[2][t].x * b4.x + a[2][t].y * b4.y + a[2][t].z * b4.z + a[2][t].w * b4.w;
            a3 += a[3][t].x * b4.x + a[3][t].y * b4.y + a[3][t].z * b4.z + a[3][t].w * b4.w;
        }

        // merge-tree reduction: 7 shuffles, lane r in {0..3} ends with acc r
        const float c01 = (odd1 ? a1 : a0) + __shfl_xor(odd1 ? a0 : a1, 1, 64);
        const float c23 = (odd1 ? a3 : a2) + __shfl_xor(odd1 ? a2 : a3, 1, 64);
        float c = (odd2 ? c23 : c01) + __shfl_xor(odd2 ? c01 : c23, 2, 64);
        c += __shfl_xor(c, 4, 64);
        c += __shfl_xor(c, 8, 64);
        c += __shfl_xor(c, 16, 64);
        c += __shfl_xor(c, 32, 64);

        if (lane < 4) {
            const int i = i0 + lane;
            D[i * BN + j] = c;
            D[j * BN + i] = c;             // mirror (bitwise-identical value)
        }
    }
}

// ---------------------------------------------------------------------------
// Kernel B: loss from D. Grid 8 x 256; block handles 32 rows. 8 blocks means
// ZERO latency hiding — every serial phase is exposed wall-clock, so this
// round removes the serialization:
//   * center-index build: ballot + popcount rank (parallel, ~50 cyc) replaces
//     the former thread-0 sequential 256-iter LDS scan (~0.6-0.9 us).
//   * si: batched independent loads (4 in flight) instead of one dependent
//     load per loop iteration; adds kept in ascending-m order -> bitwise
//     identical to the previous accepted kernel.
//   * cc: computed redundantly per-thread from LDS in the same ascending-m
//     add order (bitwise identical), removing the thread-0 phase + one sync.
//   * main pass: j4 = q*8+sub -> adjacent lanes read one contiguous 128 B
//     segment per 8-lane row group (was 128 B-strided 16 B requests).
//     pos/neg are pure min/max over the same j set -> bitwise identical.
//   * D diagonal load issued first (independent of targets) to overlap.
// Row layout: 8 threads per row (sub = tid&7 covers 32 j's); pos/neg reduced
// via shfl_xor 1/2/4; identical reduction tree and 8-block atomicAdd as the
// accepted kernel -> output bitwise unchanged (absmax stays 0.0).
// ---------------------------------------------------------------------------
__global__ __launch_bounds__(256) void finish_kernel(const float* __restrict__ D,
                                                     const int* __restrict__ targets,
                                                     float* __restrict__ out) {
    const int tid = threadIdx.x;
    const int blk = blockIdx.x;

    __shared__ int   s_t[BN];
    __shared__ float s_s[BN];
    __shared__ float s_inv[BN];
    __shared__ int   s_idx[64];
    __shared__ unsigned long long s_mask[4];
    __shared__ float s_red[4];

    const int   t_own = targets[tid];
    const float dii   = D[tid * BN + tid];     // independent: issue before sync
    s_t[tid] = t_own;
    __syncthreads();

    const int tc = s_t[BN - 4];                // last center's target id
    const unsigned long long wmask = __ballot(t_own == tc);
    if ((tid & 63) == 0) s_mask[tid >> 6] = wmask;
    __syncthreads();

    const unsigned long long m0 = s_mask[0], m1 = s_mask[1],
                             m2 = s_mask[2], m3 = s_mask[3];
    const int c0 = __popcll(m0), c1 = __popcll(m1), c2 = __popcll(m2);
    const int cnt = c0 + c1 + c2 + __popcll(m3);
    if (t_own == tc) {                         // parallel rank -> ascending order
        const int lane = tid & 63;
        const int w    = tid >> 6;
        int rank = __popcll(wmask & ((1ULL << lane) - 1ULL));
        rank += (w > 0 ? c0 : 0) + (w > 1 ? c1 : 0) + (w > 2 ? c2 : 0);
        s_idx[rank] = tid;
    }
    __syncthreads();

    const float invc = 1.0f / (float)cnt;

    // si: batches of 4 independent loads; adds in ascending-m order
    float si = 0.f;
    for (int mb = 0; mb < cnt; mb += 4) {
        float v[4];
#pragma unroll
        for (int u = 0; u < 4; ++u)
            v[u] = (mb + u < cnt) ? D[s_idx[mb + u] * BN + tid] : 0.f;
#pragma unroll
        for (int u = 0; u < 4; ++u) si += v[u];
    }
    si *= invc;
    s_s[tid] = si;
    __syncthreads();

    // cc: redundant per-thread, same ascending-m sequential add order
    float cc = 0.f;
    for (int mb = 0; mb < cnt; mb += 4) {
        float v[4];
#pragma unroll
        for (int u = 0; u < 4; ++u)
            v[u] = (mb + u < cnt) ? s_s[s_idx[mb + u]] : 0.f;
#pragma unroll
        for (int u = 0; u < 4; ++u) cc += v[u];
    }
    cc *= invc;

    const float nrm2 = fmaxf(dii - 2.f * si + cc, 0.f);
    const float inv  = 1.0f / fmaxf(sqrtf(nrm2), EPSF);
    s_inv[tid] = inv;
    __syncthreads();

    const int   row  = blk * 32 + (tid >> 3);
    const int   sub  = tid & 7;
    const int   ti   = s_t[row];
    const float siR  = s_s[row];
    const float invR = s_inv[row];

    float pos = INFINITY;
    float neg = 0.f;
    const float4* __restrict__ D4 = (const float4*)D;
#pragma unroll
    for (int q = 0; q < 8; ++q) {
        const int j4 = q * 8 + sub;            // coalesced: 128 B contiguous / 8 lanes
        const float4 d = D4[row * (BN / 4) + j4];
        const int j = 4 * j4;
        const float g0 = (d.x - siR - s_s[j + 0] + cc) * invR * s_inv[j + 0];
        const float g1 = (d.y - siR - s_s[j + 1] + cc) * invR * s_inv[j + 1];
        const float g2 = (d.z - siR - s_s[j + 2] + cc) * invR * s_inv[j + 2];
        const float g3 = (d.w - siR - s_s[j + 3] + cc) * invR * s_inv[j + 3];
        if (s_t[j + 0] == ti) pos = fminf(pos, g0); else neg = fmaxf(neg, fmaxf(g0, 0.f));
        if (s_t[j + 1] == ti) pos = fminf(pos, g1); else neg = fmaxf(neg, fmaxf(g1, 0.f));
        if (s_t[j + 2] == ti) pos = fminf(pos, g2); else neg = fmaxf(neg, fmaxf(g2, 0.f));
        if (s_t[j + 3] == ti) pos = fminf(pos, g3); else neg = fmaxf(neg, fmaxf(g3, 0.f));
    }
    // reduce pos/neg across the 8 sub-threads of this row (contiguous lanes)
#pragma unroll
    for (int off = 1; off <= 4; off <<= 1) {
        pos = fminf(pos, __shfl_xor(pos, off, 64));
        neg = fmaxf(neg, __shfl_xor(neg, off, 64));
    }
    float val = (sub == 0) ? expf(neg - pos) : 0.f;
#pragma unroll
    for (int off = 1; off <= 32; off <<= 1) val += __shfl_xor(val, off, 64);
    if ((tid & 63) == 0) s_red[tid >> 6] = val;
    __syncthreads();
    if (tid == 0)
        atomicAdd(out, (s_red[0] + s_red[1] + s_red[2] + s_red[3]) * (1.0f / 448.0f));
}

extern "C" void kernel_launch(void* const* d_in, const int* in_sizes, int n_in,
                              void* d_out, int out_size, void* d_ws, size_t ws_size,
                              hipStream_t stream) {
    const float* in      = (const float*)d_in[0];
    const int*   targets = (const int*)d_in[1];
    // d_in[2] (subs) is unused by the reference.

    float* D   = (float*)d_ws;               // 256*256 floats = 256 KB
    float* out = (float*)d_out;

    gram_kernel  <<<512, 256, 0, stream>>>(in, D, out);
    finish_kernel<<<8,   256, 0, stream>>>(D, targets, out);
}